// Round 1
// 1060.804 us; speedup vs baseline: 1.1427x; 1.1427x over previous
//
#include <hip/hip_runtime.h>
#include <stdint.h>

// All float tensors are float32 (per reference); batch is int32; output f32.
// d_ws layout: ws[0 .. G*6) = polar accumulator (f32), zeroed each call.

__device__ __forceinline__ float fast_rcp(float x) {
    return __builtin_amdgcn_rcpf(x);
}

// 512 FMAs: acc[0..63] += 8-float input chunk (A0,A1) times 8x64 weight slab W.
#define GEMM8(ACC, W, A0, A1)                                   \
    _Pragma("unroll")                                           \
    for (int j = 0; j < 64; j++) {                              \
        float v = (ACC)[j];                                     \
        v = fmaf((A0).x, (W)[j],       v);                      \
        v = fmaf((A0).y, (W)[64 + j],  v);                      \
        v = fmaf((A0).z, (W)[128 + j], v);                      \
        v = fmaf((A0).w, (W)[192 + j], v);                      \
        v = fmaf((A1).x, (W)[256 + j], v);                      \
        v = fmaf((A1).y, (W)[320 + j], v);                      \
        v = fmaf((A1).z, (W)[384 + j], v);                      \
        v = fmaf((A1).w, (W)[448 + j], v);                      \
        (ACC)[j] = v;                                           \
    }

__global__ __launch_bounds__(256, 4) void node_kernel(
    const float* __restrict__ node_scalar,  // (N,128)
    const float* __restrict__ node_equi,    // (N,480)
    const int*   __restrict__ batch,        // (N)
    const float* __restrict__ Weq0,         // (128,64) row-major
    const float* __restrict__ beq0,         // (64)
    const float* __restrict__ Weq2,         // (32,16) row-major
    const float* __restrict__ Wout0,        // (64)
    const float* __restrict__ bout0,        // (1)
    const float* __restrict__ Wout2,        // (16)
    const float* __restrict__ Ws1,          // (128,64) row-major
    const float* __restrict__ bs1,          // (64)
    const float* __restrict__ Ws2,          // (64,2) row-major
    const float* __restrict__ bs2,          // (2)
    float* __restrict__ polar,              // (G,6) f32 accumulator
    int N)
{
    int n = blockIdx.x * 256 + threadIdx.x;
    if (n >= N) return;
    int b = batch[n];                       // hoisted; needed only at the end

    float acc[64];

    // ---------- phase 1: s = silu(ns@Ws1 + bs1) @ Ws2 + bs2 ----------------
#pragma unroll
    for (int j = 0; j < 64; j++) acc[j] = 0.f;
    const float4* nsr = (const float4*)(node_scalar + (size_t)n * 128);
    {
        float4 a0 = nsr[0], a1 = nsr[1];        // chunk 0
#pragma unroll 1
        for (int c = 0; c < 15; c++) {
            float4 b0 = nsr[2 * c + 2], b1 = nsr[2 * c + 3];  // prefetch c+1
            const float* w = Ws1 + c * 512;     // wave-uniform -> s_load
            GEMM8(acc, w, a0, a1);
            a0 = b0; a1 = b1;
        }
        GEMM8(acc, Ws1 + 15 * 512, a0, a1);     // peeled tail
    }
    float sA = bs2[0], sB = bs2[1];
#pragma unroll
    for (int j = 0; j < 64; j++) {
        float h = acc[j] + bs1[j];
        float t = h * fast_rcp(1.f + __expf(-h));      // silu(h)
        sA = fmaf(t, Ws2[2 * j],     sA);
        sB = fmaf(t, Ws2[2 * j + 1], sB);
    }

    // ---------- phase 2: o0 = (g0 @ Wout0) * 64^-0.5 + b --------------------
#pragma unroll
    for (int j = 0; j < 64; j++) acc[j] = 0.f;
    const float4* x0r = (const float4*)(node_equi + (size_t)n * 480);
    {
        float4 a0 = x0r[0], a1 = x0r[1];
#pragma unroll 1
        for (int c = 0; c < 15; c++) {
            float4 b0 = x0r[2 * c + 2], b1 = x0r[2 * c + 3];
            const float* w = Weq0 + c * 512;
            GEMM8(acc, w, a0, a1);
            a0 = b0; a1 = b1;
        }
        GEMM8(acc, Weq0 + 15 * 512, a0, a1);
    }
    float o0 = 0.f;
#pragma unroll
    for (int j = 0; j < 64; j++) {
        float h = fmaf(acc[j], 0.08838834764831845f, beq0[j]); // *128^-0.5 + b
        float r = sqrtf(fmaf(h, h, 1e-12f));           // sqrt(h^2 + EPS)
        float g = h * (r * fast_rcp(1.f + __expf(-r))); // h * silu(r)
        o0 = fmaf(g, Wout0[j], o0);
    }
    o0 = fmaf(o0, 0.125f, bout0[0]);               // *64^-0.5 + b

    // ---------- phase 3: o2 path (32x16x5 einsum), two k-halves -------------
    // acc order over m (0..31 ascending) and k (0..15 ascending) is identical
    // to the single-pass version -> bit-identical accumulation.
    const float4* x2r = (const float4*)(node_equi + (size_t)n * 480 + 320);
    float o2[5] = { 0.f, 0.f, 0.f, 0.f, 0.f };
    const float S32 = 0.17677669529663687f;        // 32^-0.5
#pragma unroll 1
    for (int kc = 0; kc < 2; kc++) {
        float acc2h[40];                           // [kk*5 + i], kk = k - kc*8
#pragma unroll
        for (int t = 0; t < 40; t++) acc2h[t] = 0.f;
        // double-buffered 4-m chunks (20 floats = 5 float4 per chunk)
        float4 c0 = x2r[0], c1 = x2r[1], c2 = x2r[2], c3 = x2r[3], c4 = x2r[4];
#pragma unroll 1
        for (int mc = 0; mc < 8; mc++) {
            float4 n0, n1, n2, n3, n4;
            if (mc < 7) {
                n0 = x2r[mc * 5 + 5]; n1 = x2r[mc * 5 + 6];
                n2 = x2r[mc * 5 + 7]; n3 = x2r[mc * 5 + 8];
                n4 = x2r[mc * 5 + 9];
            }
            float f[20] = { c0.x, c0.y, c0.z, c0.w, c1.x,
                            c1.y, c1.z, c1.w, c2.x, c2.y,
                            c2.z, c2.w, c3.x, c3.y, c3.z,
                            c3.w, c4.x, c4.y, c4.z, c4.w };
#pragma unroll
            for (int mm = 0; mm < 4; mm++) {
                float v0 = f[mm * 5 + 0], v1 = f[mm * 5 + 1],
                      v2 = f[mm * 5 + 2], v3 = f[mm * 5 + 3],
                      v4 = f[mm * 5 + 4];
                const float* wq = Weq2 + (mc * 4 + mm) * 16 + kc * 8; // uniform
#pragma unroll
                for (int kk = 0; kk < 8; kk++) {
                    float wk = wq[kk];
                    acc2h[kk * 5 + 0] = fmaf(v0, wk, acc2h[kk * 5 + 0]);
                    acc2h[kk * 5 + 1] = fmaf(v1, wk, acc2h[kk * 5 + 1]);
                    acc2h[kk * 5 + 2] = fmaf(v2, wk, acc2h[kk * 5 + 2]);
                    acc2h[kk * 5 + 3] = fmaf(v3, wk, acc2h[kk * 5 + 3]);
                    acc2h[kk * 5 + 4] = fmaf(v4, wk, acc2h[kk * 5 + 4]);
                }
            }
            c0 = n0; c1 = n1; c2 = n2; c3 = n3; c4 = n4;
        }
#pragma unroll
        for (int kk = 0; kk < 8; kk++) {
            float h0 = acc2h[kk * 5 + 0] * S32, h1 = acc2h[kk * 5 + 1] * S32,
                  h2 = acc2h[kk * 5 + 2] * S32, h3 = acc2h[kk * 5 + 3] * S32,
                  h4 = acc2h[kk * 5 + 4] * S32;
            float nn = sqrtf(h0 * h0 + h1 * h1 + h2 * h2 + h3 * h3 +
                             h4 * h4 + 1e-12f);
            float sil = nn * fast_rcp(1.f + __expf(-nn));  // silu(n2)
            float fct = sil * Wout2[kc * 8 + kk];
            o2[0] = fmaf(h0, fct, o2[0]); o2[1] = fmaf(h1, fct, o2[1]);
            o2[2] = fmaf(h2, fct, o2[2]); o2[3] = fmaf(h3, fct, o2[3]);
            o2[4] = fmaf(h4, fct, o2[4]);
        }
    }

    // ---------- segment-sum -------------------------------------------------
    float* p = polar + (size_t)b * 6;
    atomicAdd(p + 0, o0 * sA);
    float q = 0.25f * sB;                          // 16^-0.5 * s[:,1]
    atomicAdd(p + 1, o2[0] * q);
    atomicAdd(p + 2, o2[1] * q);
    atomicAdd(p + 3, o2[2] * q);
    atomicAdd(p + 4, o2[3] * q);
    atomicAdd(p + 5, o2[4] * q);
}

__global__ __launch_bounds__(256) void finalize_kernel(
    const float* __restrict__ polar, float* __restrict__ out, int G)
{
    int g = blockIdx.x * 256 + threadIdx.x;
    if (g >= G) return;
    const float* p = polar + (size_t)g * 6;
    float z = p[0], dxy = p[1], dyz = p[2], dz2 = p[3], dzx = p[4], dx2 = p[5];
    float dn = sqrtf(dxy * dxy + dyz * dyz + dz2 * dz2 + dzx * dzx + dx2 * dx2);
    const float c = 0.57735026918962576f;          // 3^-0.5
    float xx = c * (dn - dz2) + dx2 + z;
    float yy = c * (dn - dz2) - dx2 + z;
    float zz = c * (dn + 2.f * dz2) + z;
    float* o = out + (size_t)g * 9;
    o[0] = xx;  o[1] = dxy; o[2] = dzx;
    o[3] = dxy; o[4] = yy;  o[5] = dyz;
    o[6] = dzx; o[7] = dyz; o[8] = zz;
}

extern "C" void kernel_launch(void* const* d_in, const int* in_sizes, int n_in,
                              void* d_out, int out_size, void* d_ws, size_t ws_size,
                              hipStream_t stream) {
    const float* node_scalar = (const float*)d_in[0];
    const float* node_equi   = (const float*)d_in[1];
    const int*   batch       = (const int*)d_in[2];
    const float* Weq0  = (const float*)d_in[3];
    const float* beq0  = (const float*)d_in[4];
    const float* Weq2  = (const float*)d_in[5];
    const float* Wout0 = (const float*)d_in[6];
    const float* bout0 = (const float*)d_in[7];
    const float* Wout2 = (const float*)d_in[8];
    const float* Ws1   = (const float*)d_in[9];
    const float* bs1   = (const float*)d_in[10];
    const float* Ws2   = (const float*)d_in[11];
    const float* bs2   = (const float*)d_in[12];

    int N = in_sizes[0] / 128;
    int G = out_size / 9;
    float* polar = (float*)d_ws;

    hipMemsetAsync(polar, 0, (size_t)G * 6 * sizeof(float), stream);

    node_kernel<<<(N + 255) / 256, 256, 0, stream>>>(
        node_scalar, node_equi, batch,
        Weq0, beq0, Weq2, Wout0, bout0, Wout2, Ws1, bs1, Ws2, bs2,
        polar, N);

    finalize_kernel<<<(G + 255) / 256, 256, 0, stream>>>(
        polar, (float*)d_out, G);
}